// Round 12
// baseline (128.413 us; speedup 1.0000x reference)
//
#include <hip/hip_runtime.h>
#include <math.h>

#define BATCH 32
#define NN 1024
#define FF 128
#define HH 128
#define NODES 32   // nodes per block in kernel A

typedef __attribute__((ext_vector_type(8))) short short8v;   // 8 bf16
typedef __attribute__((ext_vector_type(4))) float f32x4;     // MFMA acc

__device__ __forceinline__ unsigned short f2bf(float f) {    // RNE f32->bf16
    unsigned u = __float_as_uint(f);
    u += 0x7fffu + ((u >> 16) & 1u);
    return (unsigned short)(u >> 16);
}

// ---------------- Kernel A: h = X@W -> hT bf16 [B,H,N]; a_self/a_neigh scalars
__global__ __launch_bounds__(128) void gat_hidden(
    const float* __restrict__ X,      // [B,N,F]
    const float* __restrict__ W,      // [F,H]
    const float* __restrict__ Wself,  // [H]
    const float* __restrict__ Wneigh, // [H]
    unsigned short* __restrict__ hT,  // [B,H,N] bf16
    float* __restrict__ a_self,       // [B*N]
    float* __restrict__ a_neigh)      // [B*N]
{
    __shared__ float xs[NODES][FF];      // 16 KB
    __shared__ float hs[NODES][HH + 1];  // 16.5 KB
    const int tid = threadIdx.x;
    const long base_node = (long)blockIdx.x * NODES;
    const int b = (int)(base_node >> 10);
    const int n_off = (int)(base_node & 1023);

    const float4* X4 = (const float4*)(X + base_node * FF);
    float4* xs4 = (float4*)&xs[0][0];
#pragma unroll
    for (int k = 0; k < (NODES * FF) / (4 * 128); k++)
        xs4[k * 128 + tid] = X4[k * 128 + tid];
    __syncthreads();

    float acc[NODES];
#pragma unroll
    for (int n = 0; n < NODES; n++) acc[n] = 0.f;
    const int c = tid;
    for (int fq = 0; fq < FF / 4; fq++) {
        const float w0 = W[(4 * fq + 0) * HH + c];
        const float w1 = W[(4 * fq + 1) * HH + c];
        const float w2 = W[(4 * fq + 2) * HH + c];
        const float w3 = W[(4 * fq + 3) * HH + c];
#pragma unroll
        for (int n = 0; n < NODES; n++) {
            const float4 x4 = *(const float4*)&xs[n][4 * fq];
            acc[n] += x4.x * w0 + x4.y * w1 + x4.z * w2 + x4.w * w3;
        }
    }
    // thread c holds h[base+n][c] for n=0..31  ==  hT[c][base+n]: direct write
    unsigned short* dst = hT + ((size_t)b * HH + c) * NN + n_off;
    union { uint4 q; unsigned short u[8]; } pk;
#pragma unroll
    for (int g = 0; g < 4; g++) {
#pragma unroll
        for (int e = 0; e < 8; e++) pk.u[e] = f2bf(acc[g * 8 + e]);
        *(uint4*)(dst + g * 8) = pk.q;
    }
#pragma unroll
    for (int n = 0; n < NODES; n++) hs[n][c] = acc[n];
    __syncthreads();

    if (tid < 2 * NODES) {
        const int n = tid & (NODES - 1);
        const float* wvp = (tid < NODES) ? Wself : Wneigh;
        float s = 0.f;
        for (int cc = 0; cc < HH; cc++) s += hs[n][cc] * wvp[cc];
        if (tid < NODES) a_self[base_node + n] = s;
        else             a_neigh[base_node + n] = s;
    }
}

// ---------------- Kernel B: dense flash-style P@h via MFMA.
// Block = 64 rows x 128 cols (4 waves, 16 rows each). P fragments computed
// in-register from the adjacency stream (A-layout: row=lane&15, k=(lane>>4)*8+e),
// B fragments read from hT bf16 (col=lane&15, k contiguous). No LDS, no barriers.
// Unnormalized exp (overflow-safe: logits O(10)); normalize in epilogue with
// rowsum of the bf16-rounded p (consistent with the MFMA operand).
__global__ __launch_bounds__(256) void gat_attend(
    const float* __restrict__ adj,     // [B,N,N]
    const float* __restrict__ mask,    // [B,N]
    const unsigned short* __restrict__ hT, // [B,H,N] bf16
    const float* __restrict__ a_self,  // [B*N]
    const float* __restrict__ a_neigh, // [B*N]
    const float* __restrict__ bvec,    // [H]
    float* __restrict__ out)           // [B,N,H]
{
    const int tid = threadIdx.x;
    const int lane = tid & 63;
    const int wv = tid >> 6;
    // XCD swizzle: 512 blocks; XCD x owns 4 batches (hT stays L2-local, 1 MB)
    const int xcd = blockIdx.x & 7;
    const int q = blockIdx.x >> 3;
    const int batch = xcd * 4 + (q >> 4);
    const int rtile = q & 15;
    const int r0 = batch * NN + rtile * 64;          // block's 64 rows

    if (mask[r0] == 0.f) {                           // block-uniform (768%64==0)
        float4* o4 = (float4*)(out + (size_t)r0 * HH);
        for (int k = tid; k < 64 * (HH / 4); k += 256)
            o4[k] = make_float4(0.f, 0.f, 0.f, 0.f);
        return;
    }

    const int r0w = r0 + wv * 16;                    // wave's 16-row tile
    const int li = lane & 15;                        // A row / B,D col
    const int kg8 = (lane >> 4) * 8;                 // k-slice base
    const float* adjrow = adj + (size_t)(r0w + li) * NN;
    const float* anb = a_neigh + batch * NN;
    const float asl = a_self[r0w + li];
    const unsigned short* hTcol = hT + ((size_t)batch * HH + li) * NN;

    f32x4 acc[8];
#pragma unroll
    for (int ct = 0; ct < 8; ct++)
#pragma unroll
        for (int i = 0; i < 4; i++) acc[ct][i] = 0.f;
    float rs = 0.f;

#pragma unroll 2
    for (int j0 = 0; j0 < NN; j0 += 32) {
        const float4 av0 = *(const float4*)(adjrow + j0 + kg8);
        const float4 av1 = *(const float4*)(adjrow + j0 + kg8 + 4);
        const float4 nv0 = *(const float4*)(anb + j0 + kg8);
        const float4 nv1 = *(const float4*)(anb + j0 + kg8 + 4);

        union { short8v v; unsigned short u[8]; } fa;
        float x, p;
        x = asl + nv0.x; p = (av0.x > 0.f) ? __expf(fmaxf(x, 0.2f * x)) : 0.f; fa.u[0] = f2bf(p);
        x = asl + nv0.y; p = (av0.y > 0.f) ? __expf(fmaxf(x, 0.2f * x)) : 0.f; fa.u[1] = f2bf(p);
        x = asl + nv0.z; p = (av0.z > 0.f) ? __expf(fmaxf(x, 0.2f * x)) : 0.f; fa.u[2] = f2bf(p);
        x = asl + nv0.w; p = (av0.w > 0.f) ? __expf(fmaxf(x, 0.2f * x)) : 0.f; fa.u[3] = f2bf(p);
        x = asl + nv1.x; p = (av1.x > 0.f) ? __expf(fmaxf(x, 0.2f * x)) : 0.f; fa.u[4] = f2bf(p);
        x = asl + nv1.y; p = (av1.y > 0.f) ? __expf(fmaxf(x, 0.2f * x)) : 0.f; fa.u[5] = f2bf(p);
        x = asl + nv1.z; p = (av1.z > 0.f) ? __expf(fmaxf(x, 0.2f * x)) : 0.f; fa.u[6] = f2bf(p);
        x = asl + nv1.w; p = (av1.w > 0.f) ? __expf(fmaxf(x, 0.2f * x)) : 0.f; fa.u[7] = f2bf(p);

        // rowsum of the ROUNDED p (consistent with MFMA operand)
#pragma unroll
        for (int e = 0; e < 8; e++)
            rs += __uint_as_float((unsigned)fa.u[e] << 16);

#pragma unroll
        for (int ct = 0; ct < 8; ct++) {
            const short8v bf = *(const short8v*)(hTcol + ct * 16 * NN + j0 + kg8);
            acc[ct] = __builtin_amdgcn_mfma_f32_16x16x32_bf16(fa.v, bf, acc[ct], 0, 0, 0);
        }
    }

    // full rowsum for row li: combine the 4 k-group lanes
    rs += __shfl_xor(rs, 16);
    rs += __shfl_xor(rs, 32);
    const float invr = 1.f / rs;                     // lane x holds row (x&15)'s inv
    float iv[4];
#pragma unroll
    for (int i = 0; i < 4; i++)
        iv[i] = __shfl(invr, (lane >> 4) * 4 + i);   // inv for D-row kg*4+i

#pragma unroll
    for (int ct = 0; ct < 8; ct++) {
        const float bv = bvec[ct * 16 + li];
#pragma unroll
        for (int i = 0; i < 4; i++) {
            const int r = (lane >> 4) * 4 + i;       // D row = (lane>>4)*4+reg
            out[(size_t)(r0w + r) * HH + ct * 16 + li] = acc[ct][i] * iv[i] + bv;
        }
    }
}

extern "C" void kernel_launch(void* const* d_in, const int* in_sizes, int n_in,
                              void* d_out, int out_size, void* d_ws, size_t ws_size,
                              hipStream_t stream) {
    const float* X      = (const float*)d_in[0];  // M_features [B,N,F]
    const float* adj    = (const float*)d_in[1];  // M_adjacency [B,N,N]
    const float* mask   = (const float*)d_in[2];  // [B,N]
    const float* W      = (const float*)d_in[3];  // [F,H]
    const float* bvec   = (const float*)d_in[4];  // [H]
    const float* Wself  = (const float*)d_in[5];  // [H,1]
    const float* Wneigh = (const float*)d_in[6];  // [H,1]
    float* out = (float*)d_out;

    unsigned short* hT = (unsigned short*)d_ws;               // 8 MB bf16
    float* a_self  = (float*)((char*)d_ws + (size_t)BATCH * HH * NN * 2);
    float* a_neigh = a_self + (size_t)BATCH * NN;

    gat_hidden<<<(BATCH * NN) / NODES, 128, 0, stream>>>(
        X, W, Wself, Wneigh, hT, a_self, a_neigh);
    gat_attend<<<(BATCH * NN) / 64, 256, 0, stream>>>(
        adj, mask, hT, a_self, a_neigh, bvec, out);
}

// Round 13
// 102.948 us; speedup vs baseline: 1.2474x; 1.2474x over previous
//
#include <hip/hip_runtime.h>
#include <math.h>

#define BATCH 32
#define NN 1024
#define FF 128
#define HH 128
#define NODES 32   // nodes per block in kernel A

typedef __attribute__((ext_vector_type(8))) short short8v;   // 8 bf16
typedef __attribute__((ext_vector_type(4))) float f32x4;     // MFMA acc

__device__ __forceinline__ unsigned short f2bf(float f) {    // RNE f32->bf16
    unsigned u = __float_as_uint(f);
    u += 0x7fffu + ((u >> 16) & 1u);
    return (unsigned short)(u >> 16);
}

// ---------------- Kernel A: h = X@W -> hT bf16 [B,H,N]; a_self/a_neigh scalars
__global__ __launch_bounds__(128) void gat_hidden(
    const float* __restrict__ X,      // [B,N,F]
    const float* __restrict__ W,      // [F,H]
    const float* __restrict__ Wself,  // [H]
    const float* __restrict__ Wneigh, // [H]
    unsigned short* __restrict__ hT,  // [B,H,N] bf16
    float* __restrict__ a_self,       // [B*N]
    float* __restrict__ a_neigh)      // [B*N]
{
    __shared__ float xs[NODES][FF];      // 16 KB
    __shared__ float hs[NODES][HH + 1];  // 16.5 KB
    const int tid = threadIdx.x;
    const long base_node = (long)blockIdx.x * NODES;
    const int b = (int)(base_node >> 10);
    const int n_off = (int)(base_node & 1023);

    const float4* X4 = (const float4*)(X + base_node * FF);
    float4* xs4 = (float4*)&xs[0][0];
#pragma unroll
    for (int k = 0; k < (NODES * FF) / (4 * 128); k++)
        xs4[k * 128 + tid] = X4[k * 128 + tid];
    __syncthreads();

    float acc[NODES];
#pragma unroll
    for (int n = 0; n < NODES; n++) acc[n] = 0.f;
    const int c = tid;
    for (int fq = 0; fq < FF / 4; fq++) {
        const float w0 = W[(4 * fq + 0) * HH + c];
        const float w1 = W[(4 * fq + 1) * HH + c];
        const float w2 = W[(4 * fq + 2) * HH + c];
        const float w3 = W[(4 * fq + 3) * HH + c];
#pragma unroll
        for (int n = 0; n < NODES; n++) {
            const float4 x4 = *(const float4*)&xs[n][4 * fq];
            acc[n] += x4.x * w0 + x4.y * w1 + x4.z * w2 + x4.w * w3;
        }
    }
    // thread c holds h[base+n][c] for n=0..31  ==  hT[c][base+n]: direct write
    unsigned short* dst = hT + ((size_t)b * HH + c) * NN + n_off;
    union { uint4 q; unsigned short u[8]; } pk;
#pragma unroll
    for (int g = 0; g < 4; g++) {
#pragma unroll
        for (int e = 0; e < 8; e++) pk.u[e] = f2bf(acc[g * 8 + e]);
        *(uint4*)(dst + g * 8) = pk.q;
    }
#pragma unroll
    for (int n = 0; n < NODES; n++) hs[n][c] = acc[n];
    __syncthreads();

    if (tid < 2 * NODES) {
        const int n = tid & (NODES - 1);
        const float* wvp = (tid < NODES) ? Wself : Wneigh;
        float s = 0.f;
        for (int cc = 0; cc < HH; cc++) s += hs[n][cc] * wvp[cc];
        if (tid < NODES) a_self[base_node + n] = s;
        else             a_neigh[base_node + n] = s;
    }
}

// ---------------- Kernel B: dense flash-style P@h via MFMA, k-split across waves.
// Block = one 16-row tile; wave w covers cols [w*256,(w+1)*256) in 8 k-iters.
// A fragments built in-register (row=lane&15, k=(lane>>4)*8+e — m89-verified);
// B from hT bf16 (col=lane&15, k contiguous). Cross-wave combine via LDS.
// Unnormalized exp (logits O(10), overflow-safe); normalize by rowsum of the
// bf16-ROUNDED p (consistent with the MFMA operand).
__global__ __launch_bounds__(256) void gat_attend(
    const float* __restrict__ adj,     // [B,N,N]
    const float* __restrict__ mask,    // [B,N]
    const unsigned short* __restrict__ hT, // [B,H,N] bf16
    const float* __restrict__ a_self,  // [B*N]
    const float* __restrict__ a_neigh, // [B*N]
    const float* __restrict__ bvec,    // [H]
    float* __restrict__ out)           // [B,N,H]
{
    const int tid = threadIdx.x;
    const int lane = tid & 63;
    const int wv = tid >> 6;
    // XCD swizzle: 2048 blocks; XCD x owns 4 batches (hT stays L2-local)
    const int xcd = blockIdx.x & 7;
    const int q = blockIdx.x >> 3;               // [0,256)
    const int batch = xcd * 4 + (q >> 6);
    const int rtile = q & 63;
    const int r0 = batch * NN + rtile * 16;      // block's 16 rows (768%16==0)

    if (mask[r0] == 0.f) {                       // block-uniform early out
        float4* o4 = (float4*)(out + (size_t)r0 * HH);
        for (int k = tid; k < 16 * (HH / 4); k += 256)
            o4[k] = make_float4(0.f, 0.f, 0.f, 0.f);
        return;
    }

    __shared__ f32x4 accs[3][8][64];             // waves 1..3 partials, 24 KB
    __shared__ float rsum[4][64];                // 1 KB

    const int li = lane & 15;                    // A row / B,D col
    const int kg8 = (lane >> 4) * 8;             // k-slice base
    const float* adjrow = adj + (size_t)(r0 + li) * NN;
    const float* anb = a_neigh + batch * NN;
    const float asl = a_self[r0 + li];
    const unsigned short* hTcol = hT + ((size_t)batch * HH + li) * NN;
    const int j0base = wv * 256;                 // wave's k-chunk

    f32x4 acc[8];
#pragma unroll
    for (int ct = 0; ct < 8; ct++)
#pragma unroll
        for (int i = 0; i < 4; i++) acc[ct][i] = 0.f;
    float rs = 0.f;

#pragma unroll 2
    for (int it = 0; it < 8; ++it) {
        const int j0 = j0base + it * 32;
        const float4 av0 = *(const float4*)(adjrow + j0 + kg8);
        const float4 av1 = *(const float4*)(adjrow + j0 + kg8 + 4);
        const float4 nv0 = *(const float4*)(anb + j0 + kg8);
        const float4 nv1 = *(const float4*)(anb + j0 + kg8 + 4);

        union { short8v v; unsigned short u[8]; } fa;
        float x, p;
        x = asl + nv0.x; p = (av0.x > 0.f) ? __expf(fmaxf(x, 0.2f * x)) : 0.f; fa.u[0] = f2bf(p);
        x = asl + nv0.y; p = (av0.y > 0.f) ? __expf(fmaxf(x, 0.2f * x)) : 0.f; fa.u[1] = f2bf(p);
        x = asl + nv0.z; p = (av0.z > 0.f) ? __expf(fmaxf(x, 0.2f * x)) : 0.f; fa.u[2] = f2bf(p);
        x = asl + nv0.w; p = (av0.w > 0.f) ? __expf(fmaxf(x, 0.2f * x)) : 0.f; fa.u[3] = f2bf(p);
        x = asl + nv1.x; p = (av1.x > 0.f) ? __expf(fmaxf(x, 0.2f * x)) : 0.f; fa.u[4] = f2bf(p);
        x = asl + nv1.y; p = (av1.y > 0.f) ? __expf(fmaxf(x, 0.2f * x)) : 0.f; fa.u[5] = f2bf(p);
        x = asl + nv1.z; p = (av1.z > 0.f) ? __expf(fmaxf(x, 0.2f * x)) : 0.f; fa.u[6] = f2bf(p);
        x = asl + nv1.w; p = (av1.w > 0.f) ? __expf(fmaxf(x, 0.2f * x)) : 0.f; fa.u[7] = f2bf(p);

#pragma unroll
        for (int e = 0; e < 8; e++)
            rs += __uint_as_float((unsigned)fa.u[e] << 16);

#pragma unroll
        for (int ct = 0; ct < 8; ct++) {
            const short8v bf = *(const short8v*)(hTcol + ct * 16 * NN + j0 + kg8);
            acc[ct] = __builtin_amdgcn_mfma_f32_16x16x32_bf16(fa.v, bf, acc[ct], 0, 0, 0);
        }
    }

    // row li's partial over this wave's 256-col chunk
    rs += __shfl_xor(rs, 16);
    rs += __shfl_xor(rs, 32);
    rsum[wv][lane] = rs;
    if (wv > 0) {
#pragma unroll
        for (int ct = 0; ct < 8; ct++) accs[wv - 1][ct][lane] = acc[ct];
    }
    __syncthreads();

    if (wv == 0) {
        const float rtot = rsum[0][lane] + rsum[1][lane] + rsum[2][lane] + rsum[3][lane];
        const float invr = 1.f / rtot;           // lane x holds row (x&15)'s inv
        float iv[4];
#pragma unroll
        for (int i = 0; i < 4; i++)
            iv[i] = __shfl(invr, (lane >> 4) * 4 + i);   // inv for D-row (lane>>4)*4+i

#pragma unroll
        for (int ct = 0; ct < 8; ct++) {
            const f32x4 p0 = accs[0][ct][lane];
            const f32x4 p1 = accs[1][ct][lane];
            const f32x4 p2 = accs[2][ct][lane];
            const float bv = bvec[ct * 16 + li];
#pragma unroll
            for (int i = 0; i < 4; i++) {
                const int r = (lane >> 4) * 4 + i;       // D row
                const float a = acc[ct][i] + p0[i] + p1[i] + p2[i];
                out[(size_t)(r0 + r) * HH + ct * 16 + li] = a * iv[i] + bv;
            }
        }
    }
}

extern "C" void kernel_launch(void* const* d_in, const int* in_sizes, int n_in,
                              void* d_out, int out_size, void* d_ws, size_t ws_size,
                              hipStream_t stream) {
    const float* X      = (const float*)d_in[0];  // M_features [B,N,F]
    const float* adj    = (const float*)d_in[1];  // M_adjacency [B,N,N]
    const float* mask   = (const float*)d_in[2];  // [B,N]
    const float* W      = (const float*)d_in[3];  // [F,H]
    const float* bvec   = (const float*)d_in[4];  // [H]
    const float* Wself  = (const float*)d_in[5];  // [H,1]
    const float* Wneigh = (const float*)d_in[6];  // [H,1]
    float* out = (float*)d_out;

    unsigned short* hT = (unsigned short*)d_ws;               // 8 MB bf16
    float* a_self  = (float*)((char*)d_ws + (size_t)BATCH * HH * NN * 2);
    float* a_neigh = a_self + (size_t)BATCH * NN;

    gat_hidden<<<(BATCH * NN) / NODES, 128, 0, stream>>>(
        X, W, Wself, Wneigh, hT, a_self, a_neigh);
    gat_attend<<<(BATCH * NN) / 16, 256, 0, stream>>>(
        adj, mask, hT, a_self, a_neigh, bvec, out);
}

// Round 14
// 92.107 us; speedup vs baseline: 1.3942x; 1.1177x over previous
//
#include <hip/hip_runtime.h>
#include <math.h>

#define BATCH 32
#define NN 1024
#define FF 128
#define HH 128
#define NODES 32   // nodes per block in kernel A

typedef __attribute__((ext_vector_type(8))) short short8v;   // 8 bf16
typedef __attribute__((ext_vector_type(4))) float f32x4;     // MFMA acc

__device__ __forceinline__ unsigned short f2bf(float f) {    // RNE f32->bf16
    unsigned u = __float_as_uint(f);
    u += 0x7fffu + ((u >> 16) & 1u);
    return (unsigned short)(u >> 16);
}

// ---------------- Kernel A: h = X@W -> g (MFMA-B-fragment-swizzled bf16);
// a_self / a_neigh scalars.
// g element (batch, kc, ct, lane=kg*16+li, e) = h[kc*32+kg*8+e][ct*16+li]
__global__ __launch_bounds__(128) void gat_hidden(
    const float* __restrict__ X,      // [B,N,F]
    const float* __restrict__ W,      // [F,H]
    const float* __restrict__ Wself,  // [H]
    const float* __restrict__ Wneigh, // [H]
    unsigned short* __restrict__ g,   // [B][32 kc][8 ct][64 lane][8] bf16
    float* __restrict__ a_self,       // [B*N]
    float* __restrict__ a_neigh)      // [B*N]
{
    __shared__ float xs[NODES][FF];      // 16 KB
    __shared__ float hs[NODES][HH + 1];  // 16.5 KB
    const int tid = threadIdx.x;
    const long base_node = (long)blockIdx.x * NODES;
    const int batch = (int)(base_node >> 10);
    const int kc = (int)((base_node & 1023) >> 5);   // 32-node chunk index

    const float4* X4 = (const float4*)(X + base_node * FF);
    float4* xs4 = (float4*)&xs[0][0];
#pragma unroll
    for (int k = 0; k < (NODES * FF) / (4 * 128); k++)
        xs4[k * 128 + tid] = X4[k * 128 + tid];
    __syncthreads();

    float acc[NODES];
#pragma unroll
    for (int n = 0; n < NODES; n++) acc[n] = 0.f;
    const int c = tid;
    for (int fq = 0; fq < FF / 4; fq++) {
        const float w0 = W[(4 * fq + 0) * HH + c];
        const float w1 = W[(4 * fq + 1) * HH + c];
        const float w2 = W[(4 * fq + 2) * HH + c];
        const float w3 = W[(4 * fq + 3) * HH + c];
#pragma unroll
        for (int n = 0; n < NODES; n++) {
            const float4 x4 = *(const float4*)&xs[n][4 * fq];
            acc[n] += x4.x * w0 + x4.y * w1 + x4.z * w2 + x4.w * w3;
        }
    }
    // thread c = channel: ct = c>>4, li = c&15. acc[n] = h[base+n][c].
    {
        const int ct = c >> 4, li = c & 15;
        unsigned short* gb = g + ((((size_t)batch * 32 + kc) * 8 + ct) * 64) * 8;
        union { uint4 q; unsigned short u[8]; } pk;
#pragma unroll
        for (int kg = 0; kg < 4; kg++) {
#pragma unroll
            for (int e = 0; e < 8; e++) pk.u[e] = f2bf(acc[kg * 8 + e]);
            *(uint4*)(gb + (kg * 16 + li) * 8) = pk.q;
        }
    }
#pragma unroll
    for (int n = 0; n < NODES; n++) hs[n][c] = acc[n];
    __syncthreads();

    if (tid < 2 * NODES) {
        const int n = tid & (NODES - 1);
        const float* wvp = (tid < NODES) ? Wself : Wneigh;
        float s = 0.f;
        for (int cc = 0; cc < HH; cc++) s += hs[n][cc] * wvp[cc];
        if (tid < NODES) a_self[base_node + n] = s;
        else             a_neigh[base_node + n] = s;
    }
}

// ---------------- Kernel B: dense P@h via MFMA. ONE WAVE per block.
// Block = 16-row tile x 512-col k-chunk (2 chunks per tile). No LDS, no barriers.
// A fragments in-register (row=lane&15, k=(lane>>4)*8+e — R12/R13-verified);
// B from swizzled g (one coalesced 1KB load per ct). Partials to workspace.
// Unnormalized exp (logits O(10), overflow-safe); rowsum uses bf16-ROUNDED p.
__global__ __launch_bounds__(64) void gat_attend(
    const float* __restrict__ adj,     // [B,N,N]
    const float* __restrict__ mask,    // [B,N]
    const unsigned short* __restrict__ g, // swizzled bf16 h
    const float* __restrict__ a_self,  // [B*N]
    const float* __restrict__ a_neigh, // [B*N]
    float* __restrict__ part0,         // [B*N][H] f32 partial (chunk 0)
    float* __restrict__ part1,         // [B*N][H] f32 partial (chunk 1)
    float* __restrict__ rs0,           // [B*N] rowsum partial (chunk 0)
    float* __restrict__ rs1)           // [B*N]
{
    const int lane = threadIdx.x;
    // XCD swizzle: 4096 blocks; xcd owns 4 batches.
    const int b = blockIdx.x;
    const int xcd = b & 7;
    const int rest = b >> 3;                 // 0..511
    const int batch = xcd * 4 + (rest >> 7); // 4 batches per xcd
    const int idx = rest & 127;
    const int tile = idx >> 1;               // 0..63
    const int chunk = idx & 1;
    const int r0 = batch * NN + tile * 16;

    if (mask[r0] == 0.f) return;             // invalid tile: combine zero-fills

    const int li = lane & 15;
    const int kg8 = (lane >> 4) * 8;
    const float* adjrow = adj + (size_t)(r0 + li) * NN;
    const float* anb = a_neigh + batch * NN;
    const float asl = a_self[r0 + li];
    const unsigned short* gb = g + (size_t)batch * 131072;   // 32*8*64*8
    const int j0base = chunk * 512;

    f32x4 acc[8];
#pragma unroll
    for (int ct = 0; ct < 8; ct++)
#pragma unroll
        for (int i = 0; i < 4; i++) acc[ct][i] = 0.f;
    float rs = 0.f;

#pragma unroll 4
    for (int it = 0; it < 16; ++it) {
        const int j0 = j0base + it * 32;
        const int kc = j0 >> 5;
        const float4 av0 = *(const float4*)(adjrow + j0 + kg8);
        const float4 av1 = *(const float4*)(adjrow + j0 + kg8 + 4);
        const float4 nv0 = *(const float4*)(anb + j0 + kg8);
        const float4 nv1 = *(const float4*)(anb + j0 + kg8 + 4);

        union { short8v v; unsigned short u[8]; } fa;
        float x, p;
        x = asl + nv0.x; p = (av0.x > 0.f) ? __expf(fmaxf(x, 0.2f * x)) : 0.f; fa.u[0] = f2bf(p);
        x = asl + nv0.y; p = (av0.y > 0.f) ? __expf(fmaxf(x, 0.2f * x)) : 0.f; fa.u[1] = f2bf(p);
        x = asl + nv0.z; p = (av0.z > 0.f) ? __expf(fmaxf(x, 0.2f * x)) : 0.f; fa.u[2] = f2bf(p);
        x = asl + nv0.w; p = (av0.w > 0.f) ? __expf(fmaxf(x, 0.2f * x)) : 0.f; fa.u[3] = f2bf(p);
        x = asl + nv1.x; p = (av1.x > 0.f) ? __expf(fmaxf(x, 0.2f * x)) : 0.f; fa.u[4] = f2bf(p);
        x = asl + nv1.y; p = (av1.y > 0.f) ? __expf(fmaxf(x, 0.2f * x)) : 0.f; fa.u[5] = f2bf(p);
        x = asl + nv1.z; p = (av1.z > 0.f) ? __expf(fmaxf(x, 0.2f * x)) : 0.f; fa.u[6] = f2bf(p);
        x = asl + nv1.w; p = (av1.w > 0.f) ? __expf(fmaxf(x, 0.2f * x)) : 0.f; fa.u[7] = f2bf(p);

#pragma unroll
        for (int e = 0; e < 8; e++)
            rs += __uint_as_float((unsigned)fa.u[e] << 16);

#pragma unroll
        for (int ct = 0; ct < 8; ct++) {
            const short8v bf = *(const short8v*)(gb + ((size_t)(kc * 8 + ct) * 64 + lane) * 8);
            acc[ct] = __builtin_amdgcn_mfma_f32_16x16x32_bf16(fa.v, bf, acc[ct], 0, 0, 0);
        }
    }

    // chunk rowsum for row li (combine kg lanes)
    rs += __shfl_xor(rs, 16);
    rs += __shfl_xor(rs, 32);
    float* rsP = chunk ? rs1 : rs0;
    if (lane < 16) rsP[r0 + lane] = rs;

    // partial D in out-layout: row=(lane>>4)*4+i, col=ct*16+li
    float* pP = chunk ? part1 : part0;
#pragma unroll
    for (int ct = 0; ct < 8; ct++)
#pragma unroll
        for (int i = 0; i < 4; i++) {
            const int r = (lane >> 4) * 4 + i;
            pP[(size_t)(r0 + r) * HH + ct * 16 + li] = acc[ct][i];
        }
}

// ---------------- Kernel C: combine partials, normalize, bias, mask. Streaming.
__global__ __launch_bounds__(256) void gat_combine(
    const float* __restrict__ mask,
    const float* __restrict__ part0, const float* __restrict__ part1,
    const float* __restrict__ rs0, const float* __restrict__ rs1,
    const float* __restrict__ bvec,
    float* __restrict__ out)
{
    const int t = threadIdx.x;
    const int row = blockIdx.x * 8 + (t >> 5);       // 8 rows per block
    const int c4 = (t & 31) * 4;
    const size_t o = (size_t)row * HH + c4;

    if (mask[row] == 0.f) {
        *(float4*)(out + o) = make_float4(0.f, 0.f, 0.f, 0.f);
        return;
    }
    const float4 a = *(const float4*)(part0 + o);
    const float4 b = *(const float4*)(part1 + o);
    const float inv = 1.f / (rs0[row] + rs1[row]);
    const float4 bv = *(const float4*)(bvec + c4);
    float4 r;
    r.x = (a.x + b.x) * inv + bv.x;
    r.y = (a.y + b.y) * inv + bv.y;
    r.z = (a.z + b.z) * inv + bv.z;
    r.w = (a.w + b.w) * inv + bv.w;
    *(float4*)(out + o) = r;
}

extern "C" void kernel_launch(void* const* d_in, const int* in_sizes, int n_in,
                              void* d_out, int out_size, void* d_ws, size_t ws_size,
                              hipStream_t stream) {
    const float* X      = (const float*)d_in[0];  // M_features [B,N,F]
    const float* adj    = (const float*)d_in[1];  // M_adjacency [B,N,N]
    const float* mask   = (const float*)d_in[2];  // [B,N]
    const float* W      = (const float*)d_in[3];  // [F,H]
    const float* bvec   = (const float*)d_in[4];  // [H]
    const float* Wself  = (const float*)d_in[5];  // [H,1]
    const float* Wneigh = (const float*)d_in[6];  // [H,1]
    float* out = (float*)d_out;

    // workspace layout (bytes):
    // g: 8 MB | a_self: 128KB | a_neigh: 128KB | rs0,rs1: 128KB each |
    // part0: 16 MB | part1: 16 MB   (total ~40.5 MB)
    char* wsb = (char*)d_ws;
    unsigned short* g = (unsigned short*)wsb;
    const size_t GSZ = (size_t)BATCH * NN * HH * 2;          // 8 MB
    float* a_self  = (float*)(wsb + GSZ);
    float* a_neigh = a_self + (size_t)BATCH * NN;
    float* rs0     = a_neigh + (size_t)BATCH * NN;
    float* rs1     = rs0 + (size_t)BATCH * NN;
    float* part0   = rs1 + (size_t)BATCH * NN;
    float* part1   = part0 + (size_t)BATCH * NN * HH;

    gat_hidden<<<(BATCH * NN) / NODES, 128, 0, stream>>>(
        X, W, Wself, Wneigh, g, a_self, a_neigh);
    gat_attend<<<(BATCH * NN / 16) * 2, 64, 0, stream>>>(
        adj, mask, g, a_self, a_neigh, part0, part1, rs0, rs1);
    gat_combine<<<(BATCH * NN) / 8, 256, 0, stream>>>(
        mask, part0, part1, rs0, rs1, bvec, out);
}

// Round 15
// 70.085 us; speedup vs baseline: 1.8323x; 1.3142x over previous
//
#include <hip/hip_runtime.h>
#include <math.h>

#define BATCH 32
#define NN 1024
#define FF 128
#define HH 128
#define NODES 32   // nodes per block in kernel A

typedef __attribute__((ext_vector_type(8))) short short8v;   // 8 bf16
typedef __attribute__((ext_vector_type(4))) float f32x4;     // MFMA acc

__device__ __forceinline__ unsigned short f2bf(float f) {    // RNE f32->bf16
    unsigned u = __float_as_uint(f);
    u += 0x7fffu + ((u >> 16) & 1u);
    return (unsigned short)(u >> 16);
}

// ---------------- Kernel A: h = X@W -> g (MFMA-B-fragment-swizzled bf16);
// a_self / a_neigh scalars.  g[(batch,kc,ct,lane=kg*16+li,e)] = h[kc*32+kg*8+e][ct*16+li]
__global__ __launch_bounds__(128) void gat_hidden(
    const float* __restrict__ X,      // [B,N,F]
    const float* __restrict__ W,      // [F,H]
    const float* __restrict__ Wself,  // [H]
    const float* __restrict__ Wneigh, // [H]
    unsigned short* __restrict__ g,   // [B][32 kc][8 ct][64 lane][8] bf16
    float* __restrict__ a_self,       // [B*N]
    float* __restrict__ a_neigh)      // [B*N]
{
    __shared__ float xs[NODES][FF];      // 16 KB
    __shared__ float hs[NODES][HH + 1];  // 16.5 KB
    const int tid = threadIdx.x;
    const long base_node = (long)blockIdx.x * NODES;
    const int batch = (int)(base_node >> 10);
    const int kc = (int)((base_node & 1023) >> 5);   // 32-node chunk index

    const float4* X4 = (const float4*)(X + base_node * FF);
    float4* xs4 = (float4*)&xs[0][0];
#pragma unroll
    for (int k = 0; k < (NODES * FF) / (4 * 128); k++)
        xs4[k * 128 + tid] = X4[k * 128 + tid];
    __syncthreads();

    float acc[NODES];
#pragma unroll
    for (int n = 0; n < NODES; n++) acc[n] = 0.f;
    const int c = tid;
    for (int fq = 0; fq < FF / 4; fq++) {
        const float w0 = W[(4 * fq + 0) * HH + c];
        const float w1 = W[(4 * fq + 1) * HH + c];
        const float w2 = W[(4 * fq + 2) * HH + c];
        const float w3 = W[(4 * fq + 3) * HH + c];
#pragma unroll
        for (int n = 0; n < NODES; n++) {
            const float4 x4 = *(const float4*)&xs[n][4 * fq];
            acc[n] += x4.x * w0 + x4.y * w1 + x4.z * w2 + x4.w * w3;
        }
    }
    {
        const int ct = c >> 4, li = c & 15;
        unsigned short* gb = g + ((((size_t)batch * 32 + kc) * 8 + ct) * 64) * 8;
        union { uint4 q; unsigned short u[8]; } pk;
#pragma unroll
        for (int kg = 0; kg < 4; kg++) {
#pragma unroll
            for (int e = 0; e < 8; e++) pk.u[e] = f2bf(acc[kg * 8 + e]);
            *(uint4*)(gb + (kg * 16 + li) * 8) = pk.q;
        }
    }
#pragma unroll
    for (int n = 0; n < NODES; n++) hs[n][c] = acc[n];
    __syncthreads();

    if (tid < 2 * NODES) {
        const int n = tid & (NODES - 1);
        const float* wvp = (tid < NODES) ? Wself : Wneigh;
        float s = 0.f;
        for (int cc = 0; cc < HH; cc++) s += hs[n][cc] * wvp[cc];
        if (tid < NODES) a_self[base_node + n] = s;
        else             a_neigh[base_node + n] = s;
    }
}

// ---------------- Kernel B: GEMM-style P@H. Block=256thr, tile 64rows x K512 (2 chunks).
// Reg-stage adj coalesced -> exp at staging -> padded bf16 P-tile in LDS (dbuf)
// -> MFMA (A from LDS, B from swizzled g). Partials + rowsums to ws; combine after.
#define PROW 72            // padded P-tile row (bf16 elems): banks spread by 4
__global__ __launch_bounds__(256) void gat_attend(
    const float* __restrict__ adj,     // [B,N,N]
    const float* __restrict__ mask,    // [B,N]
    const unsigned short* __restrict__ g, // swizzled bf16 h
    const float* __restrict__ a_self,  // [B*N]
    const float* __restrict__ a_neigh, // [B*N]
    float* __restrict__ part0, float* __restrict__ part1,
    float* __restrict__ rs0, float* __restrict__ rs1)
{
    const int tid = threadIdx.x;
    const int lane = tid & 63;
    const int wv = tid >> 6;
    // 1024 blocks; XCD x owns 4 batches
    const int b = blockIdx.x;
    const int xcd = b & 7;
    const int rest = b >> 3;                 // 0..127
    const int batch = xcd * 4 + (rest >> 5);
    const int idx = rest & 31;
    const int tile = idx >> 1;               // 0..15
    const int chunk = idx & 1;
    const int r0 = batch * NN + tile * 64;

    if (mask[r0] == 0.f) return;             // uniform (768%64==0); combine zero-fills

    __shared__ unsigned short P[2][64 * PROW];   // 18 KB
    __shared__ float rsums[64][16];              // 4 KB

    const int k0c = chunk * 512;
    // staging geometry: thread owns rows {i*16 + (tid>>4)}, col-f4 (tid&15)
    const int srow = tid >> 4;
    const int scf4 = tid & 15;
    const float4* arow[4];
    float aslv[4];
#pragma unroll
    for (int i = 0; i < 4; i++) {
        const int rr = i * 16 + srow;
        arow[i] = (const float4*)(adj + (size_t)(r0 + rr) * NN + k0c);
        aslv[i] = a_self[r0 + rr];
    }
    const float4* anp = (const float4*)(a_neigh + batch * NN + k0c);
    const unsigned short* gb = g + (size_t)batch * 131072;   // 32*8*64*8

    float rsp[4] = {0.f, 0.f, 0.f, 0.f};

    // ---- staging helper (macro): load iter t, exp, write P[buf]
#define STAGE(t, buf)                                                      \
    {                                                                      \
        const float4 an4 = anp[(t) * 16 + scf4];                           \
        const float4 a0 = arow[0][(t) * 16 + scf4];                        \
        const float4 a1 = arow[1][(t) * 16 + scf4];                        \
        const float4 a2 = arow[2][(t) * 16 + scf4];                        \
        const float4 a3 = arow[3][(t) * 16 + scf4];                        \
        union { unsigned short u[4]; uint2 q; } w0, w1, w2, w3;            \
        float x, p;                                                        \
        x = aslv[0] + an4.x; p = (a0.x > 0.f) ? __expf(fmaxf(x, 0.2f * x)) : 0.f; w0.u[0] = f2bf(p); rsp[0] += __uint_as_float((unsigned)w0.u[0] << 16); \
        x = aslv[0] + an4.y; p = (a0.y > 0.f) ? __expf(fmaxf(x, 0.2f * x)) : 0.f; w0.u[1] = f2bf(p); rsp[0] += __uint_as_float((unsigned)w0.u[1] << 16); \
        x = aslv[0] + an4.z; p = (a0.z > 0.f) ? __expf(fmaxf(x, 0.2f * x)) : 0.f; w0.u[2] = f2bf(p); rsp[0] += __uint_as_float((unsigned)w0.u[2] << 16); \
        x = aslv[0] + an4.w; p = (a0.w > 0.f) ? __expf(fmaxf(x, 0.2f * x)) : 0.f; w0.u[3] = f2bf(p); rsp[0] += __uint_as_float((unsigned)w0.u[3] << 16); \
        x = aslv[1] + an4.x; p = (a1.x > 0.f) ? __expf(fmaxf(x, 0.2f * x)) : 0.f; w1.u[0] = f2bf(p); rsp[1] += __uint_as_float((unsigned)w1.u[0] << 16); \
        x = aslv[1] + an4.y; p = (a1.y > 0.f) ? __expf(fmaxf(x, 0.2f * x)) : 0.f; w1.u[1] = f2bf(p); rsp[1] += __uint_as_float((unsigned)w1.u[1] << 16); \
        x = aslv[1] + an4.z; p = (a1.z > 0.f) ? __expf(fmaxf(x, 0.2f * x)) : 0.f; w1.u[2] = f2bf(p); rsp[1] += __uint_as_float((unsigned)w1.u[2] << 16); \
        x = aslv[1] + an4.w; p = (a1.w > 0.f) ? __expf(fmaxf(x, 0.2f * x)) : 0.f; w1.u[3] = f2bf(p); rsp[1] += __uint_as_float((unsigned)w1.u[3] << 16); \
        x = aslv[2] + an4.x; p = (a2.x > 0.f) ? __expf(fmaxf(x, 0.2f * x)) : 0.f; w2.u[0] = f2bf(p); rsp[2] += __uint_as_float((unsigned)w2.u[0] << 16); \
        x = aslv[2] + an4.y; p = (a2.y > 0.f) ? __expf(fmaxf(x, 0.2f * x)) : 0.f; w2.u[1] = f2bf(p); rsp[2] += __uint_as_float((unsigned)w2.u[1] << 16); \
        x = aslv[2] + an4.z; p = (a2.z > 0.f) ? __expf(fmaxf(x, 0.2f * x)) : 0.f; w2.u[2] = f2bf(p); rsp[2] += __uint_as_float((unsigned)w2.u[2] << 16); \
        x = aslv[2] + an4.w; p = (a2.w > 0.f) ? __expf(fmaxf(x, 0.2f * x)) : 0.f; w2.u[3] = f2bf(p); rsp[2] += __uint_as_float((unsigned)w2.u[3] << 16); \
        x = aslv[3] + an4.x; p = (a3.x > 0.f) ? __expf(fmaxf(x, 0.2f * x)) : 0.f; w3.u[0] = f2bf(p); rsp[3] += __uint_as_float((unsigned)w3.u[0] << 16); \
        x = aslv[3] + an4.y; p = (a3.y > 0.f) ? __expf(fmaxf(x, 0.2f * x)) : 0.f; w3.u[1] = f2bf(p); rsp[3] += __uint_as_float((unsigned)w3.u[1] << 16); \
        x = aslv[3] + an4.z; p = (a3.z > 0.f) ? __expf(fmaxf(x, 0.2f * x)) : 0.f; w3.u[2] = f2bf(p); rsp[3] += __uint_as_float((unsigned)w3.u[2] << 16); \
        x = aslv[3] + an4.w; p = (a3.w > 0.f) ? __expf(fmaxf(x, 0.2f * x)) : 0.f; w3.u[3] = f2bf(p); rsp[3] += __uint_as_float((unsigned)w3.u[3] << 16); \
        *(uint2*)&P[buf][(0 * 16 + srow) * PROW + scf4 * 4] = w0.q;        \
        *(uint2*)&P[buf][(1 * 16 + srow) * PROW + scf4 * 4] = w1.q;        \
        *(uint2*)&P[buf][(2 * 16 + srow) * PROW + scf4 * 4] = w2.q;        \
        *(uint2*)&P[buf][(3 * 16 + srow) * PROW + scf4 * 4] = w3.q;        \
    }

    f32x4 acc[8];
#pragma unroll
    for (int ct = 0; ct < 8; ct++)
#pragma unroll
        for (int i = 0; i < 4; i++) acc[ct][i] = 0.f;

    // prologue: stage iter 0 into P[0]
    STAGE(0, 0)
    __syncthreads();

    const int li = lane & 15;
    const int kg8 = (lane >> 4) * 8;
    for (int it = 0; it < 8; ++it) {
        const int cur = it & 1;
        // MFMA on P[cur]: K = 64 = 2 k-chunks of 32
#pragma unroll
        for (int kcl = 0; kcl < 2; kcl++) {
            const short8v af = *(const short8v*)&P[cur][(wv * 16 + li) * PROW + kcl * 32 + kg8];
            const int kcG = (k0c >> 5) + it * 2 + kcl;
#pragma unroll
            for (int ct = 0; ct < 8; ct++) {
                const short8v bf = *(const short8v*)(gb + ((size_t)(kcG * 8 + ct) * 64 + lane) * 8);
                acc[ct] = __builtin_amdgcn_mfma_f32_16x16x32_bf16(af, bf, acc[ct], 0, 0, 0);
            }
        }
        if (it < 7) STAGE(it + 1, cur ^ 1)
        __syncthreads();
    }

    // rowsums: thread partials -> LDS -> per-row total
    rsums[0 * 16 + srow][scf4] = rsp[0];
    rsums[1 * 16 + srow][scf4] = rsp[1];
    rsums[2 * 16 + srow][scf4] = rsp[2];
    rsums[3 * 16 + srow][scf4] = rsp[3];
    __syncthreads();
    float* rsP = chunk ? rs1 : rs0;
    if (tid < 64) {
        float s = 0.f;
#pragma unroll
        for (int q = 0; q < 16; q++) s += rsums[tid][q];
        rsP[r0 + tid] = s;
    }

    // partial D: row=(lane>>4)*4+i (+wv*16), col=ct*16+li
    float* pP = chunk ? part1 : part0;
#pragma unroll
    for (int ct = 0; ct < 8; ct++)
#pragma unroll
        for (int i = 0; i < 4; i++) {
            const int r = wv * 16 + (lane >> 4) * 4 + i;
            pP[(size_t)(r0 + r) * HH + ct * 16 + li] = acc[ct][i];
        }
#undef STAGE
}

// ---------------- Kernel C: combine partials, normalize, bias, mask. Streaming.
__global__ __launch_bounds__(256) void gat_combine(
    const float* __restrict__ mask,
    const float* __restrict__ part0, const float* __restrict__ part1,
    const float* __restrict__ rs0, const float* __restrict__ rs1,
    const float* __restrict__ bvec,
    float* __restrict__ out)
{
    const int t = threadIdx.x;
    const int row = blockIdx.x * 8 + (t >> 5);       // 8 rows per block
    const int c4 = (t & 31) * 4;
    const size_t o = (size_t)row * HH + c4;

    if (mask[row] == 0.f) {
        *(float4*)(out + o) = make_float4(0.f, 0.f, 0.f, 0.f);
        return;
    }
    const float4 a = *(const float4*)(part0 + o);
    const float4 b = *(const float4*)(part1 + o);
    const float inv = 1.f / (rs0[row] + rs1[row]);
    const float4 bv = *(const float4*)(bvec + c4);
    float4 r;
    r.x = (a.x + b.x) * inv + bv.x;
    r.y = (a.y + b.y) * inv + bv.y;
    r.z = (a.z + b.z) * inv + bv.z;
    r.w = (a.w + b.w) * inv + bv.w;
    *(float4*)(out + o) = r;
}

extern "C" void kernel_launch(void* const* d_in, const int* in_sizes, int n_in,
                              void* d_out, int out_size, void* d_ws, size_t ws_size,
                              hipStream_t stream) {
    const float* X      = (const float*)d_in[0];  // M_features [B,N,F]
    const float* adj    = (const float*)d_in[1];  // M_adjacency [B,N,N]
    const float* mask   = (const float*)d_in[2];  // [B,N]
    const float* W      = (const float*)d_in[3];  // [F,H]
    const float* bvec   = (const float*)d_in[4];  // [H]
    const float* Wself  = (const float*)d_in[5];  // [H,1]
    const float* Wneigh = (const float*)d_in[6];  // [H,1]
    float* out = (float*)d_out;

    char* wsb = (char*)d_ws;
    unsigned short* g = (unsigned short*)wsb;
    const size_t GSZ = (size_t)BATCH * NN * HH * 2;          // 8 MB
    float* a_self  = (float*)(wsb + GSZ);
    float* a_neigh = a_self + (size_t)BATCH * NN;
    float* rs0     = a_neigh + (size_t)BATCH * NN;
    float* rs1     = rs0 + (size_t)BATCH * NN;
    float* part0   = rs1 + (size_t)BATCH * NN;
    float* part1   = part0 + (size_t)BATCH * NN * HH;

    gat_hidden<<<(BATCH * NN) / NODES, 128, 0, stream>>>(
        X, W, Wself, Wneigh, g, a_self, a_neigh);
    gat_attend<<<1024, 256, 0, stream>>>(
        adj, mask, g, a_self, a_neigh, part0, part1, rs0, rs1);
    gat_combine<<<(BATCH * NN) / 8, 256, 0, stream>>>(
        mask, part0, part1, rs0, rs1, bvec, out);
}